// Round 1
// baseline (116.734 us; speedup 1.0000x reference)
//
#include <hip/hip_runtime.h>
#include <math.h>

#define B_ 4
#define N_ 64
#define L_ 128
#define H_ 8
#define E_ 32

// qm[b][h][e][t] = mean over n of queries[b,n,t,h,e]   (fp64 accumulate)
__global__ __launch_bounds__(256) void k_qmean(const float* __restrict__ q,
                                               float* __restrict__ qm) {
    int blk = blockIdx.x;               // b*128 + t
    int b = blk >> 7, t = blk & 127;
    int c = threadIdx.x;                // h*32 + e
    const float* p = q + (((size_t)(b * N_)) * L_ + t) * 256 + c;
    double s = 0.0;
    for (int n = 0; n < N_; ++n) s += (double)p[(size_t)n * L_ * 256];
    qm[((size_t)b * 256 + c) * L_ + t] = (float)(s * (1.0 / 64.0));
}

// wT[dt][lp*32+e] = w_cf[(e*128+lp)*3 + dt],  bT[lp*32+e] = b_cf[e*128+lp]
__global__ void k_prepwb(const float* __restrict__ w, const float* __restrict__ bias,
                         float* __restrict__ wT, float* __restrict__ bT) {
    int k = blockIdx.x * 256 + threadIdx.x;  // 4096 = lp*32+e
    int e = k & 31, lp = k >> 5;
    int c = e * L_ + lp;
    wT[k]          = w[c * 3 + 0];
    wT[4096 + k]   = w[c * 3 + 1];
    wT[8192 + k]   = w[c * 3 + 2];
    bT[k]          = bias[c];
}

// part[sc][b][n][h][tau] = sum_{s in chunk sc, e} keys[b,n,s,h,e]*qm[b,h,e,(s+tau)%128]
// grid: (b*8+h)*16 + sc  (512 blocks), 256 threads, thread tile 4n x 8tau, fp64 acc
__global__ __launch_bounds__(256) void k_corr(const float* __restrict__ keys,
                                              const float* __restrict__ qm,
                                              float* __restrict__ part) {
    int blk = blockIdx.x;
    int sc = blk & 15; int bh = blk >> 4; int h = bh & 7; int b = bh >> 3;
    __shared__ float qs[E_][L_ + 1];        // 32 x 129
    __shared__ float as[4][E_][N_ + 1];     // 4 x 32 x 65
    int tid = threadIdx.x;

    for (int k = tid; k < E_ * L_; k += 256) {
        int e = k >> 7, t = k & 127;
        qs[e][t] = qm[((size_t)b * 256 + h * E_ + e) * L_ + t];
    }
    int tx = tid & 15, ty = tid >> 4;   // n = ty*4+i ; tau = tx + 16*j
    double acc[4][8];
    #pragma unroll
    for (int i = 0; i < 4; ++i)
        #pragma unroll
        for (int j = 0; j < 8; ++j) acc[i][j] = 0.0;

    for (int half = 0; half < 2; ++half) {
        __syncthreads();
        for (int k = tid; k < 4 * E_ * N_; k += 256) {
            int e = k & 31; int n = (k >> 5) & 63; int ss = k >> 11;
            int s = sc * 8 + half * 4 + ss;
            as[ss][e][n] = keys[(((size_t)(b * N_ + n)) * L_ + s) * 256 + h * E_ + e];
        }
        __syncthreads();
        #pragma unroll
        for (int ss = 0; ss < 4; ++ss) {
            int sb = sc * 8 + half * 4 + ss;
            int tt[8];
            #pragma unroll
            for (int j = 0; j < 8; ++j) tt[j] = (sb + tx + 16 * j) & 127;
            for (int e = 0; e < E_; ++e) {
                double a0 = (double)as[ss][e][ty * 4 + 0];
                double a1 = (double)as[ss][e][ty * 4 + 1];
                double a2 = (double)as[ss][e][ty * 4 + 2];
                double a3 = (double)as[ss][e][ty * 4 + 3];
                #pragma unroll
                for (int j = 0; j < 8; ++j) {
                    double bb = (double)qs[e][tt[j]];
                    acc[0][j] = fma(a0, bb, acc[0][j]);
                    acc[1][j] = fma(a1, bb, acc[1][j]);
                    acc[2][j] = fma(a2, bb, acc[2][j]);
                    acc[3][j] = fma(a3, bb, acc[3][j]);
                }
            }
        }
    }
    #pragma unroll
    for (int i = 0; i < 4; ++i) {
        int n = ty * 4 + i;
        size_t o = ((((size_t)sc * B_ + b) * N_ + n) * H_ + h) * L_;
        #pragma unroll
        for (int j = 0; j < 8; ++j) part[o + tx + 16 * j] = (float)acc[i][j];
    }
}

// top-2 over tau per (b,n,h); jax tie semantics (equal value -> lower index)
__global__ __launch_bounds__(64) void k_topk(const float* __restrict__ part,
                                             int* __restrict__ didx,
                                             float* __restrict__ sig) {
    int blk = blockIdx.x;               // (b*64+n)*8+h
    int lane = threadIdx.x;
    size_t rb = (size_t)blk * L_;
    const size_t stride = (size_t)B_ * N_ * H_ * L_;
    double s0 = 0.0, s1 = 0.0;
    for (int sc = 0; sc < 16; ++sc) {
        s0 += (double)part[sc * stride + rb + lane];
        s1 += (double)part[sc * stride + rb + lane + 64];
    }
    float v0 = (float)(s0 * (1.0 / 32.0));
    float v1 = (float)(s1 * (1.0 / 32.0));

    float bv = v0; int bi = lane;
    if (v1 > v0) { bv = v1; bi = lane + 64; }
    #pragma unroll
    for (int m = 32; m; m >>= 1) {
        float ov = __shfl_xor(bv, m, 64);
        int   oi = __shfl_xor(bi, m, 64);
        if (ov > bv || (ov == bv && oi < bi)) { bv = ov; bi = oi; }
    }
    int i1 = bi; float w1v = bv;

    float c0 = (lane == i1) ? -INFINITY : v0;
    float c1 = (lane + 64 == i1) ? -INFINITY : v1;
    float bv2 = c0; int bi2 = lane;
    if (c1 > c0) { bv2 = c1; bi2 = lane + 64; }
    #pragma unroll
    for (int m = 32; m; m >>= 1) {
        float ov = __shfl_xor(bv2, m, 64);
        int   oi = __shfl_xor(bi2, m, 64);
        if (ov > bv2 || (ov == bv2 && oi < bi2)) { bv2 = ov; bi2 = oi; }
    }
    if (lane == 0) {
        didx[blk * 2 + 0] = i1;
        didx[blk * 2 + 1] = bi2;
        sig[blk * 2 + 0] = 1.f / (1.f + expf(-w1v));
        sig[blk * 2 + 1] = 1.f / (1.f + expf(-bv2));
    }
}

// stable argsort by (delay asc, n asc) over N=64; emit sorted-order predecessors
__global__ __launch_bounds__(128) void k_sort(const int* __restrict__ didx,
                                              int* __restrict__ pred) {
    int bh = blockIdx.x;                // b*8+h
    int b = bh >> 3, h = bh & 7;
    int tid = threadIdx.x; int i = tid >> 6; int n = tid & 63;
    __shared__ int ds[2][64];
    __shared__ int pm[2][64];
    int d = 128 - didx[((b * 64 + n) * 8 + h) * 2 + i];
    ds[i][n] = d;
    __syncthreads();
    int rank = 0;
    for (int m = 0; m < 64; ++m) {
        int dm = ds[i][m];
        rank += (dm < d || (dm == d && m < n)) ? 1 : 0;
    }
    pm[i][rank] = n;
    __syncthreads();
    int p1v = (rank >= 1) ? pm[i][rank - 1] : -1;
    int p2v = (rank >= 2) ? pm[i][rank - 2] : -1;
    int o = ((bh * 2 + i) * 64 + n) * 2;
    pred[o] = p1v; pred[o + 1] = p2v;
}

// final gather: V[b,n,t,h,e] = 0.5 * sum_i [ b[c] + w2[c]*sig_n*v(n,t)
//   + w1[c]*sig_p1*v(p1,(t+di_n-di_p1)%128) + w0[c]*sig_p2*v(p2,(t+di_n-di_p2)%128) ]
__global__ __launch_bounds__(256) void k_out(const float* __restrict__ values,
                                             const float* __restrict__ wT,
                                             const float* __restrict__ bT,
                                             const int* __restrict__ didx,
                                             const float* __restrict__ sig,
                                             const int* __restrict__ pred,
                                             float* __restrict__ out) {
    int blk = blockIdx.x;               // (b*64+n)*8+h
    int h = blk & 7; int r = blk >> 3; int n = r & 63; int b = r >> 6;
    int tid = threadIdx.x; int e = tid & 31; int tr = tid >> 5;

    int di[2], dp1[2], dp2[2], p1[2], p2[2];
    float si[2], s1[2], s2[2];
    #pragma unroll
    for (int i = 0; i < 2; ++i) {
        di[i] = didx[blk * 2 + i];
        si[i] = sig[blk * 2 + i];
        int po = (((b * 8 + h) * 2 + i) * 64 + n) * 2;
        p1[i] = pred[po]; p2[i] = pred[po + 1];
        if (p1[i] >= 0) {
            int qidx = ((b * 64 + p1[i]) * 8 + h) * 2 + i;
            dp1[i] = didx[qidx]; s1[i] = sig[qidx];
        } else { dp1[i] = 0; s1[i] = 0.f; }
        if (p2[i] >= 0) {
            int qidx = ((b * 64 + p2[i]) * 8 + h) * 2 + i;
            dp2[i] = didx[qidx]; s2[i] = sig[qidx];
        } else { dp2[i] = 0; s2[i] = 0.f; }
    }
    const size_t vbase = ((size_t)b * N_) * L_ * 256 + h * E_ + e;
    const size_t obase = (((size_t)(b * N_ + n)) * L_) * 256 + h * E_ + e;

    for (int it = 0; it < 16; ++it) {
        int t = tr + 8 * it;
        float vself = values[vbase + ((size_t)n * L_ + t) * 256];
        float acc = 0.f;
        #pragma unroll
        for (int i = 0; i < 2; ++i) {
            int lp = (t + di[i]) & 127;
            int wo = lp * 32 + e;
            acc += bT[wo] + wT[8192 + wo] * si[i] * vself;
            if (p1[i] >= 0) {
                int t1 = (t + di[i] - dp1[i]) & 127;
                acc += wT[4096 + wo] * s1[i] * values[vbase + ((size_t)p1[i] * L_ + t1) * 256];
            }
            if (p2[i] >= 0) {
                int t2 = (t + di[i] - dp2[i]) & 127;
                acc += wT[wo] * s2[i] * values[vbase + ((size_t)p2[i] * L_ + t2) * 256];
            }
        }
        out[obase + (size_t)t * 256] = acc * 0.5f;
    }
}

extern "C" void kernel_launch(void* const* d_in, const int* in_sizes, int n_in,
                              void* d_out, int out_size, void* d_ws, size_t ws_size,
                              hipStream_t stream) {
    const float* queries = (const float*)d_in[0];
    const float* keys    = (const float*)d_in[1];
    const float* values  = (const float*)d_in[2];
    // d_in[3] = attn_mask (unused)
    const float* w_cf = (const float*)d_in[4];
    const float* b_cf = (const float*)d_in[5];
    float* out = (float*)d_out;

    // workspace layout (small, ~650 KB)
    float* ws    = (float*)d_ws;
    float* qm    = ws;                    // 131072 f
    float* wT    = qm + 131072;           // 12288 f
    float* bT    = wT + 12288;            // 4096 f
    float* sigp  = bT + 4096;             // 4096 f
    int*   didxp = (int*)(sigp + 4096);   // 4096 i
    int*   predp = didxp + 4096;          // 8192 i

    // 16 MB of corr partials live in d_out (written by k_corr, read by k_topk,
    // then d_out is fully overwritten by k_out)
    float* part = (float*)d_out;

    k_qmean <<<512,  256, 0, stream>>>(queries, qm);
    k_prepwb<<<16,   256, 0, stream>>>(w_cf, b_cf, wT, bT);
    k_corr  <<<512,  256, 0, stream>>>(keys, qm, part);
    k_topk  <<<2048, 64,  0, stream>>>(part, didxp, sigp);
    k_sort  <<<32,   128, 0, stream>>>(didxp, predp);
    k_out   <<<2048, 256, 0, stream>>>(values, wT, bT, didxp, sigp, predp, out);
}